// Round 8
// baseline (181.707 us; speedup 1.0000x reference)
//
#include <hip/hip_runtime.h>

typedef unsigned short u16;
typedef __bf16 bf16x8 __attribute__((ext_vector_type(8)));
typedef float f32x4 __attribute__((ext_vector_type(4)));

__device__ inline u16 f2bf(float f) {
    union { float f; unsigned int u; } a; a.f = f;
    unsigned int u = a.u + 0x7fffu + ((a.u >> 16) & 1u);
    return (u16)(u >> 16);
}

// async global->LDS, 16B per lane. LDS side is wave-uniform base + lane*16.
__device__ __forceinline__ void cp16(const void* g, void* l) {
    __builtin_amdgcn_global_load_lds(
        (const __attribute__((address_space(1))) unsigned int*)g,
        (__attribute__((address_space(3))) unsigned int*)l, 16, 0, 0);
}

// -------- prep: weight transposes only (x-cast is fused into gemm_qkv) --------
__global__ __launch_bounds__(256) void prep(
    const float* __restrict__ wq, const float* __restrict__ wo,
    u16* __restrict__ wtq, u16* __restrict__ wto)
{
    int bid = blockIdx.x;
    __shared__ u16 tile[32][33];
    const float* in; u16* outp; int N, bx, by;
    if (bid < 1728) { in = wq; outp = wtq; N = 2304; bx = bid % 72; by = bid / 72; }
    else            { int t = bid - 1728; in = wo; outp = wto; N = 768;  bx = t % 24; by = t / 24; }
    int n0 = bx * 32, k0 = by * 32;
    int tx = threadIdx.x & 31, ty = threadIdx.x >> 5;
    #pragma unroll
    for (int r = ty; r < 32; r += 8)
        tile[r][tx] = f2bf(in[(size_t)(k0 + r) * N + n0 + tx]);
    __syncthreads();
    // vectorized stores: 2 adjacent k-cols per thread -> 4B/lane
    int tx2 = threadIdx.x & 15, ty2 = threadIdx.x >> 4;
    #pragma unroll
    for (int r = ty2; r < 32; r += 16) {
        union { u16 s[2]; unsigned int v; } pk;
        pk.s[0] = tile[2 * tx2][r];
        pk.s[1] = tile[2 * tx2 + 1][r];
        *(unsigned int*)&outp[(size_t)(n0 + r) * 768 + k0 + 2 * tx2] = pk.v;
    }
}

// -------- QKV GEMM with FUSED x-cast: A read as f32, cvt in regs (2-deep), B via cp16 --------
// Skeleton = R6 dbuf counted-vmcnt (2 barriers/iter). A-regs 2-deep named sets (aX/aY):
// iter i issues A(i+2) loads, drains A(i+1)+B(i) via one vmcnt(12), ds_writes A(i+1).
// X f32 [8192][768], Bt bf16 [2304][768]
// Q (*0.125*log2e) -> [b,h,n,64]; K -> [b,h,n,64]; V -> TRANSPOSED [b,h,d,n]
__global__ __launch_bounds__(256, 2) void gemm_qkv(
    const float* __restrict__ X, const u16* __restrict__ Bt,
    u16* __restrict__ q_out, u16* __restrict__ k_out, u16* __restrict__ v_out)
{
    __shared__ __align__(16) u16 As[2][128 * 64];   // slot s of row R holds k-group s^(R&7)
    __shared__ __align__(16) u16 Bs[2][128 * 64];

    int tid = threadIdx.x;
    int lane = tid & 63, wave = tid >> 6;
    int quad = lane >> 4, l16 = lane & 15;
    int wm = wave >> 1, wn = wave & 1;
    int id = blockIdx.x;
    int xcd = id & 7, j = id >> 3;
    int m0 = (((j & 7) << 3) + xcd) * 128;   // 64 m-tiles, XCD-pinned A slabs
    int n0 = (j >> 3) * 128;                 // 18 n-tiles

    f32x4 acc[4][4];
    #pragma unroll
    for (int i = 0; i < 4; i++)
        #pragma unroll
        for (int jj = 0; jj < 4; jj++) acc[i][jj] = (f32x4){0.f, 0.f, 0.f, 0.f};

    int r0 = tid >> 3, cg = tid & 7;
    int g = cg ^ (r0 & 7);                   // row&7 == r0&7 for all 4 its
    const float* GX[4]; const u16* GB[4];
    #pragma unroll
    for (int it = 0; it < 4; it++) {
        GX[it] = X  + (size_t)(m0 + it * 32 + r0) * 768 + g * 8;   // f32 source
        GB[it] = Bt + (size_t)(n0 + it * 32 + r0) * 768 + g * 8;   // bf16 source
    }

    float4 aX[4][2], aY[4][2];   // 2-deep A staging regs (named sets, no dyn index)

    #define LOAD_A(SET, kt)                                       \
        _Pragma("unroll")                                         \
        for (int it = 0; it < 4; it++) {                          \
            SET[it][0] = *(const float4*)(GX[it] + (kt));         \
            SET[it][1] = *(const float4*)(GX[it] + (kt) + 4);     \
        }
    #define STAGE_B(kt, b)                                        \
        _Pragma("unroll")                                         \
        for (int it = 0; it < 4; it++)                            \
            cp16(GB[it] + (kt), &Bs[b][(it * 256 + tid) * 8]);
    #define WRITE_A(SET, b)                                       \
        _Pragma("unroll")                                         \
        for (int it = 0; it < 4; it++) {                          \
            union { unsigned int w[4]; uint4 v; } pk;             \
            asm("v_cvt_pk_bf16_f32 %0, %1, %2" : "=v"(pk.w[0]) : "v"(SET[it][0].x), "v"(SET[it][0].y)); \
            asm("v_cvt_pk_bf16_f32 %0, %1, %2" : "=v"(pk.w[1]) : "v"(SET[it][0].z), "v"(SET[it][0].w)); \
            asm("v_cvt_pk_bf16_f32 %0, %1, %2" : "=v"(pk.w[2]) : "v"(SET[it][1].x), "v"(SET[it][1].y)); \
            asm("v_cvt_pk_bf16_f32 %0, %1, %2" : "=v"(pk.w[3]) : "v"(SET[it][1].z), "v"(SET[it][1].w)); \
            *(uint4*)&As[b][(it * 256 + tid) * 8] = pk.v;         \
        }
    #define COMP(b)                                               \
    {                                                             \
        bf16x8 af[2][4], bfr[2][4];                               \
        _Pragma("unroll")                                         \
        for (int ko = 0; ko < 2; ko++)                            \
            _Pragma("unroll")                                     \
            for (int x = 0; x < 4; x++) {                         \
                int Ra = wm * 64 + x * 16 + l16;                  \
                af[ko][x]  = *(const bf16x8*)&As[b][Ra * 64 + (((ko * 4 + quad) ^ (Ra & 7)) * 8)]; \
                int Rb = wn * 64 + x * 16 + l16;                  \
                bfr[ko][x] = *(const bf16x8*)&Bs[b][Rb * 64 + (((ko * 4 + quad) ^ (Rb & 7)) * 8)]; \
            }                                                     \
        _Pragma("unroll")                                         \
        for (int ko = 0; ko < 2; ko++)                            \
            _Pragma("unroll")                                     \
            for (int x = 0; x < 4; x++)                           \
                _Pragma("unroll")                                 \
                for (int y = 0; y < 4; y++)                       \
                    acc[x][y] = __builtin_amdgcn_mfma_f32_16x16x32_bf16(af[ko][x], bfr[ko][y], acc[x][y], 0, 0, 0); \
    }

    // prologue: A(0)->aX, A(1)->aY, B(0) cp16; drain A(0); write A(0)->As[0]
    LOAD_A(aX, 0)
    LOAD_A(aY, 64)
    STAGE_B(0, 0)
    asm volatile("s_waitcnt vmcnt(12)" ::: "memory");   // drain A(0); A(1)8+B(0)4 in flight
    WRITE_A(aX, 0)

    for (int ii = 0; ii < 5; ii++) {
        int i0 = 2 * ii;                      // even iter, b=0
        LOAD_A(aX, (i0 + 2) * 64)             // A(i0+2) -> aX (freed by prior write)
        STAGE_B((i0 + 1) * 64, 1)             // B(i0+1) -> Bs[1]
        asm volatile("s_waitcnt vmcnt(12)" ::: "memory");  // drain A(i0+1)+B(i0)
        WRITE_A(aY, 1)                        // A(i0+1) -> As[1]
        asm volatile("s_waitcnt lgkmcnt(0)" ::: "memory");
        __builtin_amdgcn_s_barrier();
        COMP(0)
        __builtin_amdgcn_s_barrier();         // WAR trailing

        int i1 = i0 + 1;                      // odd iter, b=1
        LOAD_A(aY, (i1 + 2) * 64)
        STAGE_B((i1 + 1) * 64, 0)
        asm volatile("s_waitcnt vmcnt(12)" ::: "memory");  // drain A(i1+1)+B(i1)
        WRITE_A(aX, 0)
        asm volatile("s_waitcnt lgkmcnt(0)" ::: "memory");
        __builtin_amdgcn_s_barrier();
        COMP(1)
        __builtin_amdgcn_s_barrier();
    }
    // after loop: aY=A(11); As[0]=A(10); Bs[0]=B(10) staged; outstanding A(11)8+B(10)4
    // iter 10 (b=0): no A(12)
    STAGE_B(11 * 64, 1)                       // B(11) -> Bs[1]
    asm volatile("s_waitcnt vmcnt(4)" ::: "memory");       // drain A(11)+B(10), keep B(11)
    WRITE_A(aY, 1)                            // A(11) -> As[1]
    asm volatile("s_waitcnt lgkmcnt(0)" ::: "memory");
    __builtin_amdgcn_s_barrier();
    COMP(0)
    __builtin_amdgcn_s_barrier();
    // iter 11 (b=1)
    asm volatile("s_waitcnt vmcnt(0)" ::: "memory");       // drain B(11)
    asm volatile("s_waitcnt lgkmcnt(0)" ::: "memory");
    __builtin_amdgcn_s_barrier();
    COMP(1)
    __builtin_amdgcn_s_barrier();

    #undef LOAD_A
    #undef STAGE_B
    #undef WRITE_A
    #undef COMP

    // ---- epilogue: wave tile = 64m x 64n, one (part,h); per-wave LDS region in buf0 ----
    int M0 = m0 + wm * 64, N0 = n0 + wn * 64;
    int part = N0 >= 1536 ? 2 : (N0 >= 768 ? 1 : 0);
    int h = (N0 - part * 768) >> 6;
    int b2 = M0 >> 10, npos0 = M0 & 1023;
    u16* ep = (wave < 2 ? As[0] : Bs[0]) + (wave & 1) * 4096;   // 8 KB per wave (buf0: free)

    if (part != 2) {
        float scale = (part == 0) ? 0.18033688011112042f : 1.0f;   // /8 * log2e for Q
        u16* gbase = (part == 0 ? q_out : k_out) + (((size_t)(b2 * 12 + h) * 1024 + npos0) << 6);
        #pragma unroll
        for (int i = 0; i < 4; i++)
            #pragma unroll
            for (int jj = 0; jj < 4; jj++) {
                int dd = jj * 16 + l16;
                #pragma unroll
                for (int r = 0; r < 4; r++) {
                    int np = i * 16 + quad * 4 + r;
                    ep[np * 64 + (((dd >> 3) ^ (np & 7)) * 8) + (dd & 7)] =
                        f2bf(acc[i][jj][r] * scale);
                }
            }
        #pragma unroll
        for (int t = 0; t < 8; t++) {        // per-wave region: ds order suffices, no barrier
            int idx = t * 512 + lane * 8;
            int np = idx >> 6;
            int slot = ((lane & 7) ^ (np & 7));
            uint4 v = *(const uint4*)&ep[np * 64 + slot * 8];
            *(uint4*)&gbase[idx] = v;
        }
    } else {
        #pragma unroll
        for (int i = 0; i < 4; i++)
            #pragma unroll
            for (int jj = 0; jj < 4; jj++) {
                int dd = jj * 16 + l16;
                int npg = i * 2 + (quad >> 1);
                int sub = (quad & 1) * 4;
                union { u16 s[4]; uint2 v; } pk;
                #pragma unroll
                for (int r = 0; r < 4; r++) pk.s[r] = f2bf(acc[i][jj][r]);
                *(uint2*)&ep[dd * 64 + ((npg ^ (dd & 7)) * 8) + sub] = pk.v;
            }
        #pragma unroll
        for (int t = 0; t < 8; t++) {
            int dd = t * 8 + (lane >> 3);
            int npg = lane & 7;
            uint4 v = *(const uint4*)&ep[dd * 64 + ((npg ^ (dd & 7)) * 8)];
            *(uint4*)&v_out[((size_t)((b2 * 12 + h) * 64 + dd)) * 1024 + npos0 + npg * 8] = v;
        }
    }
}

// -------- attention: 8 waves (512 thr), 16 q/wave, 1 barrier/iter (R4-exact FROZEN text) --------
__global__ __launch_bounds__(512, 6) void attn128(
    u16* __restrict__ QO, const u16* __restrict__ Kg, const u16* __restrict__ Vtg)
{
    __shared__ __align__(16) u16 Ks[2][64 * 64];   // [kv][d], 16B groups at pos g^(row&7)
    __shared__ __align__(16) u16 Vs[2][64 * 64];   // [d][kv], 8B chunks at pos c^(d&15)

    int tid = threadIdx.x;
    int lane = tid & 63, wave = tid >> 6;          // 8 waves
    int quad = lane >> 4, l16 = lane & 15;
    int id = blockIdx.x;
    int xcd = id & 7, j = id >> 3;                 // 12 heads per XCD
    int bh = xcd * 12 + (j >> 3);
    int q0 = (j & 7) * 128;
    const size_t head_base = (size_t)bh * 65536;

    size_t qoff = head_base + (size_t)(q0 + wave * 16 + l16) * 64;
    bf16x8 qf0 = *(const bf16x8*)&QO[qoff + quad * 8];
    bf16x8 qf1 = *(const bf16x8*)&QO[qoff + 32 + quad * 8];

    f32x4 Oacc[4];
    #pragma unroll
    for (int dt = 0; dt < 4; dt++) Oacc[dt] = (f32x4){0.f, 0.f, 0.f, 0.f};
    f32x4 lacc = (f32x4){0.f, 0.f, 0.f, 0.f};

    // ones A-fragment for l = sum_k P[k][q] via MFMA
    union { unsigned int w[4]; bf16x8 v; } ones;
    ones.w[0] = ones.w[1] = ones.w[2] = ones.w[3] = 0x3f803f80u;

    int srow = tid >> 3, sg = tid & 7;             // 512 thr cover 64 rows x 128B
    int gsK = sg ^ (srow & 7);
    const u16* GK = Kg + head_base + (size_t)srow * 64 + gsK * 8;
    const u16* GV = Vtg + head_base + (size_t)srow * 1024 + sg * 8;
    const int vwA = srow * 64 + (((2 * sg)     ^ (srow & 15)) * 4);
    const int vwB = srow * 64 + (((2 * sg + 1) ^ (srow & 15)) * 4);

    uint4 vA, vB;
    // prologue: V(0) -> LDS direct; V(1) -> regs; K(0) cp16
    {
        uint4 t0 = *(const uint4*)GV;
        uint2 t;
        t.x = t0.x; t.y = t0.y; *(uint2*)&Vs[0][vwA] = t;
        t.x = t0.z; t.y = t0.w; *(uint2*)&Vs[0][vwB] = t;
    }
    vA = *(const uint4*)(GV + 64);
    cp16(GK, &Ks[0][tid * 8]);

    // one barrier per iter; prefetch issued after it, drained at next iter's vmcnt(0)
    #define ATT_STEP(I, DO_K, DO_LD, VLD, DO_WR, VWR)                            \
    {                                                                            \
        const int b = (I) & 1;                                                   \
        asm volatile("s_waitcnt vmcnt(0)" ::: "memory");                         \
        asm volatile("s_waitcnt lgkmcnt(0)" ::: "memory");                       \
        __builtin_amdgcn_s_barrier();                                            \
        if (DO_K) cp16(GK + (size_t)((I) + 1) * 4096, &Ks[b ^ 1][tid * 8]);      \
        if (DO_LD) VLD = *(const uint4*)(GV + ((I) + 2) * 64);                   \
        if (DO_WR) {                                                             \
            uint2 t;                                                             \
            t.x = VWR.x; t.y = VWR.y; *(uint2*)&Vs[b ^ 1][vwA] = t;              \
            t.x = VWR.z; t.y = VWR.w; *(uint2*)&Vs[b ^ 1][vwB] = t;              \
        }                                                                        \
        f32x4 s4[4];                                                             \
        _Pragma("unroll")                                                        \
        for (int nt = 0; nt < 4; nt++) {                                         \
            int R = nt * 16 + l16;                                               \
            bf16x8 kf0 = *(const bf16x8*)&Ks[b][R * 64 + ((quad       ^ (R & 7)) * 8)]; \
            bf16x8 kf1 = *(const bf16x8*)&Ks[b][R * 64 + (((quad + 4) ^ (R & 7)) * 8)]; \
            f32x4 s = (f32x4){0.f, 0.f, 0.f, 0.f};                               \
            s = __builtin_amdgcn_mfma_f32_16x16x32_bf16(kf0, qf0, s, 0, 0, 0);   \
            s = __builtin_amdgcn_mfma_f32_16x16x32_bf16(kf1, qf1, s, 0, 0, 0);   \
            s4[nt] = s;                                                          \
        }                                                                        \
        float p[4][4];                                                           \
        _Pragma("unroll")                                                        \
        for (int nt = 0; nt < 4; nt++)                                           \
            _Pragma("unroll")                                                    \
            for (int r = 0; r < 4; r++)                                          \
                p[nt][r] = __builtin_amdgcn_exp2f(s4[nt][r]);                    \
        __builtin_amdgcn_s_setprio(1);                                           \
        _Pragma("unroll")                                                        \
        for (int h = 0; h < 2; h++) {                                            \
            union { unsigned int w[4]; bf16x8 v; } pk;                           \
            asm("v_cvt_pk_bf16_f32 %0, %1, %2" : "=v"(pk.w[0]) : "v"(p[2*h][0]),   "v"(p[2*h][1]));   \
            asm("v_cvt_pk_bf16_f32 %0, %1, %2" : "=v"(pk.w[1]) : "v"(p[2*h][2]),   "v"(p[2*h][3]));   \
            asm("v_cvt_pk_bf16_f32 %0, %1, %2" : "=v"(pk.w[2]) : "v"(p[2*h+1][0]), "v"(p[2*h+1][1])); \
            asm("v_cvt_pk_bf16_f32 %0, %1, %2" : "=v"(pk.w[3]) : "v"(p[2*h+1][2]), "v"(p[2*h+1][3])); \
            lacc = __builtin_amdgcn_mfma_f32_16x16x32_bf16(ones.v, pk.v, lacc, 0, 0, 0); \
            int pbase = ((8 * h + quad) ^ l16) * 4;                              \
            _Pragma("unroll")                                                    \
            for (int dt = 0; dt < 4; dt++) {                                     \
                int drow = dt * 16 + l16;                                        \
                union { u16 s[8]; bf16x8 v; } vk;                                \
                *(uint2*)&vk.s[0] = *(const uint2*)&Vs[b][drow * 64 + pbase];    \
                *(uint2*)&vk.s[4] = *(const uint2*)&Vs[b][drow * 64 + (pbase ^ 16)]; \
                Oacc[dt] = __builtin_amdgcn_mfma_f32_16x16x32_bf16(vk.v, pk.v, Oacc[dt], 0, 0, 0); \
            }                                                                    \
        }                                                                        \
        __builtin_amdgcn_s_setprio(0);                                           \
    }

    // main: unrolled x2 so V reg sets alternate with no copies
    for (int ii = 0; ii < 7; ii++) {
        ATT_STEP(2 * ii,     1, 1, vB, 1, vA)      // write V(i+1)=vA, load V(i+2)->vB
        ATT_STEP(2 * ii + 1, 1, 1, vA, 1, vB)
    }
    ATT_STEP(14, 1, 0, vB, 1, vA)                  // K(15) only; write V(15)=vA
    ATT_STEP(15, 0, 0, vA, 0, vB)                  // drain & compute last tile
    #undef ATT_STEP

    {
        float rl = __builtin_amdgcn_rcpf(lacc[0]);   // l for col q=l16 (rows identical)
        #pragma unroll
        for (int dt = 0; dt < 4; dt++) {
            union { u16 s[4]; uint2 v; } ok;
            #pragma unroll
            for (int r = 0; r < 4; r++) ok.s[r] = f2bf(Oacc[dt][r] * rl);
            *(uint2*)&QO[qoff + dt * 16 + quad * 4] = ok.v;
        }
    }
}

// -------- out-proj GEMM: 128m x 64n, 768 blocks, dbuf counted-vmcnt (R6-exact text) --------
__global__ __launch_bounds__(256) void gemm_out(
    const u16* __restrict__ Qg, const u16* __restrict__ Bt,
    const float* __restrict__ bias, float* __restrict__ out)
{
    const int K = 768;
    __shared__ __align__(16) u16 As[2][128 * 64];   // 16 KB each
    __shared__ __align__(16) u16 Bs[2][64 * 64];    // 8 KB each  (total 48 KB)

    int tid = threadIdx.x;
    int lane = tid & 63, wave = tid >> 6;
    int quad = lane >> 4, l16 = lane & 15;
    int wm = wave >> 1, wn = wave & 1;               // wave tile: 64m x 32n
    int id = blockIdx.x;
    int xcd = id & 7, j = id >> 3;                   // j in [0,96)
    int m0 = (((j & 7) << 3) + xcd) * 128;           // 64 m-tiles, XCD-pinned
    int n0 = (j >> 3) * 64;                          // 12 n-tiles

    f32x4 acc[4][2];
    #pragma unroll
    for (int i = 0; i < 4; i++)
        #pragma unroll
        for (int jj = 0; jj < 2; jj++) acc[i][jj] = (f32x4){0.f, 0.f, 0.f, 0.f};

    int r0 = tid >> 3, cg = tid & 7;
    int g = cg ^ (r0 & 7);
    const u16* GA[4]; const u16* GB[2];
    #pragma unroll
    for (int it = 0; it < 4; it++) {
        int m = m0 + it * 32 + r0, b = m >> 10, npos = m & 1023;
        GA[it] = Qg + (((size_t)(b * 12) * 1024 + npos) << 6) + g * 8;  // + h*65536
    }
    #pragma unroll
    for (int it = 0; it < 2; it++)
        GB[it] = Bt + (size_t)(n0 + it * 32 + r0) * K + g * 8;          // + kt

    #define STAGE_OUT(i2, b)                                              \
        _Pragma("unroll")                                                 \
        for (int it = 0; it < 4; it++)                                    \
            cp16(GA[it] + (size_t)(i2) * 65536, &As[b][(it * 256 + tid) * 8]); \
        _Pragma("unroll")                                                 \
        for (int it = 0; it < 2; it++)                                    \
            cp16(GB[it] + (i2) * 64,            &Bs[b][(it * 256 + tid) * 8]);

    STAGE_OUT(0, 0)
    for (int i = 0; i < 12; i++) {
        int b = i & 1;
        if (i + 1 < 12) {
            STAGE_OUT(i + 1, b ^ 1)
            asm volatile("s_waitcnt vmcnt(6)" ::: "memory");
        } else {
            asm volatile("s_waitcnt vmcnt(0)" ::: "memory");
        }
        __builtin_amdgcn_s_barrier();
        bf16x8 af[2][4], bfr[2][2];
        #pragma unroll
        for (int ko = 0; ko < 2; ko++) {
            #pragma unroll
            for (int x = 0; x < 4; x++) {
                int Ra = wm * 64 + x * 16 + l16;
                af[ko][x]  = *(const bf16x8*)&As[b][Ra * 64 + (((ko * 4 + quad) ^ (Ra & 7)) * 8)];
            }
            #pragma unroll
            for (int y = 0; y < 2; y++) {
                int Rb = wn * 32 + y * 16 + l16;
                bfr[ko][y] = *(const bf16x8*)&Bs[b][Rb * 64 + (((ko * 4 + quad) ^ (Rb & 7)) * 8)];
            }
        }
        #pragma unroll
        for (int ko = 0; ko < 2; ko++)
            #pragma unroll
            for (int x = 0; x < 4; x++)
                #pragma unroll
                for (int y = 0; y < 2; y++)
                    acc[x][y] = __builtin_amdgcn_mfma_f32_16x16x32_bf16(af[ko][x], bfr[ko][y], acc[x][y], 0, 0, 0);
        __builtin_amdgcn_s_barrier();
    }
    #undef STAGE_OUT

    #pragma unroll
    for (int i = 0; i < 4; i++) {
        int mbase = m0 + wm * 64 + i * 16 + quad * 4;
        #pragma unroll
        for (int jj = 0; jj < 2; jj++) {
            int n = n0 + wn * 32 + jj * 16 + l16;
            float bv = bias[n];
            #pragma unroll
            for (int r = 0; r < 4; r++)
                out[(size_t)(mbase + r) * 768 + n] = acc[i][jj][r] + bv;
        }
    }
}

extern "C" void kernel_launch(void* const* d_in, const int* in_sizes, int n_in,
                              void* d_out, int out_size, void* d_ws, size_t ws_size,
                              hipStream_t stream) {
    const float* x     = (const float*)d_in[0];   // [8,1024,768] f32
    const float* w_qkv = (const float*)d_in[1];   // [768,2304] f32
    const float* w_out = (const float*)d_in[2];   // [768,768] f32
    const float* b_out = (const float*)d_in[3];   // [768] f32
    float* out = (float*)d_out;                   // [8,1024,768] f32

    char* ws = (char*)d_ws;
    u16* wtq  = (u16*)(ws);                   // [2304][768] bf16    3,538,944 B
    u16* wto  = (u16*)(ws + 3538944);         // [768][768]  bf16    1,179,648 B
    u16* Qbuf = (u16*)(ws + 4718592);         // [8,12,1024,64] bf16 12,582,912 B
    // K natural [b,h,n,64] and V TRANSPOSED [b,h,64,n] live in d_out (2x12.58 MB);
    // both fully consumed by attn128 before gemm_out overwrites d_out.
    u16* Kbuf = (u16*)d_out;
    u16* Vbuf = (u16*)d_out + 6291456;

    prep<<<dim3(2304), 256, 0, stream>>>(w_qkv, w_out, wtq, wto);
    gemm_qkv<<<dim3(1152), 256, 0, stream>>>(x, wtq, Qbuf, Kbuf, Vbuf);
    attn128<<<dim3(768), 512, 0, stream>>>(Qbuf, Kbuf, Vbuf);
    gemm_out<<<dim3(768), 256, 0, stream>>>(Qbuf, wto, b_out, out);
}

// Round 9
// 180.043 us; speedup vs baseline: 1.0092x; 1.0092x over previous
//
#include <hip/hip_runtime.h>

typedef unsigned short u16;
typedef __bf16 bf16x8 __attribute__((ext_vector_type(8)));
typedef float f32x4 __attribute__((ext_vector_type(4)));

__device__ inline u16 f2bf(float f) {
    union { float f; unsigned int u; } a; a.f = f;
    unsigned int u = a.u + 0x7fffu + ((a.u >> 16) & 1u);
    return (u16)(u >> 16);
}

// async global->LDS, 16B per lane. LDS side is wave-uniform base + lane*16.
__device__ __forceinline__ void cp16(const void* g, void* l) {
    __builtin_amdgcn_global_load_lds(
        (const __attribute__((address_space(1))) unsigned int*)g,
        (__attribute__((address_space(3))) unsigned int*)l, 16, 0, 0);
}

// -------- prep: fuse x-cast + both weight transposes (1 launch; R6-exact) --------
__global__ __launch_bounds__(256) void prep(
    const float* __restrict__ x, const float* __restrict__ wq,
    const float* __restrict__ wo, u16* __restrict__ xbf,
    u16* __restrict__ wtq, u16* __restrict__ wto)
{
    int bid = blockIdx.x;
    if (bid < 3072) {                      // cast x: f32 -> bf16, 8/thread
        size_t base = ((size_t)bid * 256 + threadIdx.x) * 8;
        float4 f0 = *(const float4*)&x[base];
        float4 f1 = *(const float4*)&x[base + 4];
        union { u16 s[8]; uint4 v; } t;
        t.s[0]=f2bf(f0.x); t.s[1]=f2bf(f0.y); t.s[2]=f2bf(f0.z); t.s[3]=f2bf(f0.w);
        t.s[4]=f2bf(f1.x); t.s[5]=f2bf(f1.y); t.s[6]=f2bf(f1.z); t.s[7]=f2bf(f1.w);
        *(uint4*)&xbf[base] = t.v;
        return;
    }
    __shared__ u16 tile[32][33];
    const float* in; u16* outp; int N, bx, by;
    if (bid < 3072 + 1728) { int t = bid - 3072; in = wq; outp = wtq; N = 2304; bx = t % 72; by = t / 72; }
    else                   { int t = bid - 4800; in = wo; outp = wto; N = 768;  bx = t % 24; by = t / 24; }
    int n0 = bx * 32, k0 = by * 32;
    int tx = threadIdx.x & 31, ty = threadIdx.x >> 5;
    #pragma unroll
    for (int r = ty; r < 32; r += 8)
        tile[r][tx] = f2bf(in[(size_t)(k0 + r) * N + n0 + tx]);
    __syncthreads();
    // vectorized stores: 2 adjacent k-cols per thread -> 4B/lane
    int tx2 = threadIdx.x & 15, ty2 = threadIdx.x >> 4;
    #pragma unroll
    for (int r = ty2; r < 32; r += 16) {
        union { u16 s[2]; unsigned int v; } pk;
        pk.s[0] = tile[2 * tx2][r];
        pk.s[1] = tile[2 * tx2 + 1][r];
        *(unsigned int*)&outp[(size_t)(n0 + r) * 768 + k0 + 2 * tx2] = pk.v;
    }
}

// -------- QKV GEMM: BK=64, dbuf, 1 barrier/iter (stage-after-barrier), XCD-pinned --------
// WAR safety: each wave's ds_reads of buf b complete (lgkmcnt before its MFMAs) before it
// reaches the next barrier, so post-barrier cp16 into b^1 / next-next into b is race-free.
// A bf16 [8192][768], Bt bf16 [2304][768]
// Q (*0.125*log2e) -> [b,h,n,64]; K -> [b,h,n,64]; V -> TRANSPOSED [b,h,d,n]
__global__ __launch_bounds__(256) void gemm_qkv(
    const u16* __restrict__ A, const u16* __restrict__ Bt,
    u16* __restrict__ q_out, u16* __restrict__ k_out, u16* __restrict__ v_out)
{
    const int K = 768;
    __shared__ __align__(16) u16 As[2][128 * 64];   // slot s of row R holds k-group s^(R&7)
    __shared__ __align__(16) u16 Bs[2][128 * 64];

    int tid = threadIdx.x;
    int lane = tid & 63, wave = tid >> 6;
    int quad = lane >> 4, l16 = lane & 15;
    int wm = wave >> 1, wn = wave & 1;
    int id = blockIdx.x;
    int xcd = id & 7, j = id >> 3;
    int m0 = (((j & 7) << 3) + xcd) * 128;   // 64 m-tiles, XCD-pinned A slabs
    int n0 = (j >> 3) * 128;                 // 18 n-tiles

    f32x4 acc[4][4];
    #pragma unroll
    for (int i = 0; i < 4; i++)
        #pragma unroll
        for (int jj = 0; jj < 4; jj++) acc[i][jj] = (f32x4){0.f, 0.f, 0.f, 0.f};

    int r0 = tid >> 3, cg = tid & 7;
    int g = cg ^ (r0 & 7);                   // row&7 == r0&7 for all 4 its
    const u16* GA[4]; const u16* GB[4];
    #pragma unroll
    for (int it = 0; it < 4; it++) {
        GA[it] = A  + (size_t)(m0 + it * 32 + r0) * K + g * 8;
        GB[it] = Bt + (size_t)(n0 + it * 32 + r0) * K + g * 8;
    }

    #define STAGE_QKV(kt, b)                                          \
        _Pragma("unroll")                                             \
        for (int it = 0; it < 4; it++) {                              \
            cp16(GA[it] + (kt), &As[b][(it * 256 + tid) * 8]);        \
            cp16(GB[it] + (kt), &Bs[b][(it * 256 + tid) * 8]);        \
        }

    STAGE_QKV(0, 0)
    for (int i = 0; i < 12; i++) {
        int b = i & 1;
        asm volatile("s_waitcnt vmcnt(0)" ::: "memory");   // tile i's 8 loads done
        __builtin_amdgcn_s_barrier();                      // all waves: buf b ready, b^1 free
        if (i + 1 < 12) { STAGE_QKV((i + 1) * 64, b ^ 1) } // full iteration in flight
        bf16x8 af[2][4], bfr[2][4];
        #pragma unroll
        for (int ko = 0; ko < 2; ko++)
            #pragma unroll
            for (int x = 0; x < 4; x++) {
                int Ra = wm * 64 + x * 16 + l16;
                af[ko][x]  = *(const bf16x8*)&As[b][Ra * 64 + (((ko * 4 + quad) ^ (Ra & 7)) * 8)];
                int Rb = wn * 64 + x * 16 + l16;
                bfr[ko][x] = *(const bf16x8*)&Bs[b][Rb * 64 + (((ko * 4 + quad) ^ (Rb & 7)) * 8)];
            }
        #pragma unroll
        for (int ko = 0; ko < 2; ko++)
            #pragma unroll
            for (int x = 0; x < 4; x++)
                #pragma unroll
                for (int y = 0; y < 4; y++)
                    acc[x][y] = __builtin_amdgcn_mfma_f32_16x16x32_bf16(af[ko][x], bfr[ko][y], acc[x][y], 0, 0, 0);
    }
    #undef STAGE_QKV
    // last frag reads were from buf1 (i=11); buf0 reads ended before the i=11 barrier,
    // so per-wave epilogue writes into buf0 regions are safe without another barrier.

    // ---- epilogue: wave tile = 64m x 64n, one (part,h); per-wave LDS region in buf0 ----
    int M0 = m0 + wm * 64, N0 = n0 + wn * 64;
    int part = N0 >= 1536 ? 2 : (N0 >= 768 ? 1 : 0);
    int h = (N0 - part * 768) >> 6;
    int b2 = M0 >> 10, npos0 = M0 & 1023;
    u16* ep = (wave < 2 ? As[0] : Bs[0]) + (wave & 1) * 4096;   // 8 KB per wave (buf0: free)

    if (part != 2) {
        float scale = (part == 0) ? 0.18033688011112042f : 1.0f;   // /8 * log2e for Q
        u16* gbase = (part == 0 ? q_out : k_out) + (((size_t)(b2 * 12 + h) * 1024 + npos0) << 6);
        #pragma unroll
        for (int i = 0; i < 4; i++)
            #pragma unroll
            for (int jj = 0; jj < 4; jj++) {
                int dd = jj * 16 + l16;
                #pragma unroll
                for (int r = 0; r < 4; r++) {
                    int np = i * 16 + quad * 4 + r;
                    ep[np * 64 + (((dd >> 3) ^ (np & 7)) * 8) + (dd & 7)] =
                        f2bf(acc[i][jj][r] * scale);
                }
            }
        #pragma unroll
        for (int t = 0; t < 8; t++) {        // per-wave region: ds order suffices, no barrier
            int idx = t * 512 + lane * 8;
            int np = idx >> 6;
            int slot = ((lane & 7) ^ (np & 7));
            uint4 v = *(const uint4*)&ep[np * 64 + slot * 8];
            *(uint4*)&gbase[idx] = v;
        }
    } else {
        #pragma unroll
        for (int i = 0; i < 4; i++)
            #pragma unroll
            for (int jj = 0; jj < 4; jj++) {
                int dd = jj * 16 + l16;
                int npg = i * 2 + (quad >> 1);
                int sub = (quad & 1) * 4;
                union { u16 s[4]; uint2 v; } pk;
                #pragma unroll
                for (int r = 0; r < 4; r++) pk.s[r] = f2bf(acc[i][jj][r]);
                *(uint2*)&ep[dd * 64 + ((npg ^ (dd & 7)) * 8) + sub] = pk.v;
            }
        #pragma unroll
        for (int t = 0; t < 8; t++) {
            int dd = t * 8 + (lane >> 3);
            int npg = lane & 7;
            uint4 v = *(const uint4*)&ep[dd * 64 + ((npg ^ (dd & 7)) * 8)];
            *(uint4*)&v_out[((size_t)((b2 * 12 + h) * 64 + dd)) * 1024 + npos0 + npg * 8] = v;
        }
    }
}

// -------- attention: 8 waves (512 thr), 16 q/wave, 1 barrier/iter (R4-exact FROZEN text) --------
__global__ __launch_bounds__(512, 6) void attn128(
    u16* __restrict__ QO, const u16* __restrict__ Kg, const u16* __restrict__ Vtg)
{
    __shared__ __align__(16) u16 Ks[2][64 * 64];   // [kv][d], 16B groups at pos g^(row&7)
    __shared__ __align__(16) u16 Vs[2][64 * 64];   // [d][kv], 8B chunks at pos c^(d&15)

    int tid = threadIdx.x;
    int lane = tid & 63, wave = tid >> 6;          // 8 waves
    int quad = lane >> 4, l16 = lane & 15;
    int id = blockIdx.x;
    int xcd = id & 7, j = id >> 3;                 // 12 heads per XCD
    int bh = xcd * 12 + (j >> 3);
    int q0 = (j & 7) * 128;
    const size_t head_base = (size_t)bh * 65536;

    size_t qoff = head_base + (size_t)(q0 + wave * 16 + l16) * 64;
    bf16x8 qf0 = *(const bf16x8*)&QO[qoff + quad * 8];
    bf16x8 qf1 = *(const bf16x8*)&QO[qoff + 32 + quad * 8];

    f32x4 Oacc[4];
    #pragma unroll
    for (int dt = 0; dt < 4; dt++) Oacc[dt] = (f32x4){0.f, 0.f, 0.f, 0.f};
    f32x4 lacc = (f32x4){0.f, 0.f, 0.f, 0.f};

    // ones A-fragment for l = sum_k P[k][q] via MFMA
    union { unsigned int w[4]; bf16x8 v; } ones;
    ones.w[0] = ones.w[1] = ones.w[2] = ones.w[3] = 0x3f803f80u;

    int srow = tid >> 3, sg = tid & 7;             // 512 thr cover 64 rows x 128B
    int gsK = sg ^ (srow & 7);
    const u16* GK = Kg + head_base + (size_t)srow * 64 + gsK * 8;
    const u16* GV = Vtg + head_base + (size_t)srow * 1024 + sg * 8;
    const int vwA = srow * 64 + (((2 * sg)     ^ (srow & 15)) * 4);
    const int vwB = srow * 64 + (((2 * sg + 1) ^ (srow & 15)) * 4);

    uint4 vA, vB;
    // prologue: V(0) -> LDS direct; V(1) -> regs; K(0) cp16
    {
        uint4 t0 = *(const uint4*)GV;
        uint2 t;
        t.x = t0.x; t.y = t0.y; *(uint2*)&Vs[0][vwA] = t;
        t.x = t0.z; t.y = t0.w; *(uint2*)&Vs[0][vwB] = t;
    }
    vA = *(const uint4*)(GV + 64);
    cp16(GK, &Ks[0][tid * 8]);

    // one barrier per iter; prefetch issued after it, drained at next iter's vmcnt(0)
    #define ATT_STEP(I, DO_K, DO_LD, VLD, DO_WR, VWR)                            \
    {                                                                            \
        const int b = (I) & 1;                                                   \
        asm volatile("s_waitcnt vmcnt(0)" ::: "memory");                         \
        asm volatile("s_waitcnt lgkmcnt(0)" ::: "memory");                       \
        __builtin_amdgcn_s_barrier();                                            \
        if (DO_K) cp16(GK + (size_t)((I) + 1) * 4096, &Ks[b ^ 1][tid * 8]);      \
        if (DO_LD) VLD = *(const uint4*)(GV + ((I) + 2) * 64);                   \
        if (DO_WR) {                                                             \
            uint2 t;                                                             \
            t.x = VWR.x; t.y = VWR.y; *(uint2*)&Vs[b ^ 1][vwA] = t;              \
            t.x = VWR.z; t.y = VWR.w; *(uint2*)&Vs[b ^ 1][vwB] = t;              \
        }                                                                        \
        f32x4 s4[4];                                                             \
        _Pragma("unroll")                                                        \
        for (int nt = 0; nt < 4; nt++) {                                         \
            int R = nt * 16 + l16;                                               \
            bf16x8 kf0 = *(const bf16x8*)&Ks[b][R * 64 + ((quad       ^ (R & 7)) * 8)]; \
            bf16x8 kf1 = *(const bf16x8*)&Ks[b][R * 64 + (((quad + 4) ^ (R & 7)) * 8)]; \
            f32x4 s = (f32x4){0.f, 0.f, 0.f, 0.f};                               \
            s = __builtin_amdgcn_mfma_f32_16x16x32_bf16(kf0, qf0, s, 0, 0, 0);   \
            s = __builtin_amdgcn_mfma_f32_16x16x32_bf16(kf1, qf1, s, 0, 0, 0);   \
            s4[nt] = s;                                                          \
        }                                                                        \
        float p[4][4];                                                           \
        _Pragma("unroll")                                                        \
        for (int nt = 0; nt < 4; nt++)                                           \
            _Pragma("unroll")                                                    \
            for (int r = 0; r < 4; r++)                                          \
                p[nt][r] = __builtin_amdgcn_exp2f(s4[nt][r]);                    \
        __builtin_amdgcn_s_setprio(1);                                           \
        _Pragma("unroll")                                                        \
        for (int h = 0; h < 2; h++) {                                            \
            union { unsigned int w[4]; bf16x8 v; } pk;                           \
            asm("v_cvt_pk_bf16_f32 %0, %1, %2" : "=v"(pk.w[0]) : "v"(p[2*h][0]),   "v"(p[2*h][1]));   \
            asm("v_cvt_pk_bf16_f32 %0, %1, %2" : "=v"(pk.w[1]) : "v"(p[2*h][2]),   "v"(p[2*h][3]));   \
            asm("v_cvt_pk_bf16_f32 %0, %1, %2" : "=v"(pk.w[2]) : "v"(p[2*h+1][0]), "v"(p[2*h+1][1])); \
            asm("v_cvt_pk_bf16_f32 %0, %1, %2" : "=v"(pk.w[3]) : "v"(p[2*h+1][2]), "v"(p[2*h+1][3])); \
            lacc = __builtin_amdgcn_mfma_f32_16x16x32_bf16(ones.v, pk.v, lacc, 0, 0, 0); \
            int pbase = ((8 * h + quad) ^ l16) * 4;                              \
            _Pragma("unroll")                                                    \
            for (int dt = 0; dt < 4; dt++) {                                     \
                int drow = dt * 16 + l16;                                        \
                union { u16 s[8]; bf16x8 v; } vk;                                \
                *(uint2*)&vk.s[0] = *(const uint2*)&Vs[b][drow * 64 + pbase];    \
                *(uint2*)&vk.s[4] = *(const uint2*)&Vs[b][drow * 64 + (pbase ^ 16)]; \
                Oacc[dt] = __builtin_amdgcn_mfma_f32_16x16x32_bf16(vk.v, pk.v, Oacc[dt], 0, 0, 0); \
            }                                                                    \
        }                                                                        \
        __builtin_amdgcn_s_setprio(0);                                           \
    }

    // main: unrolled x2 so V reg sets alternate with no copies
    for (int ii = 0; ii < 7; ii++) {
        ATT_STEP(2 * ii,     1, 1, vB, 1, vA)      // write V(i+1)=vA, load V(i+2)->vB
        ATT_STEP(2 * ii + 1, 1, 1, vA, 1, vB)
    }
    ATT_STEP(14, 1, 0, vB, 1, vA)                  // K(15) only; write V(15)=vA
    ATT_STEP(15, 0, 0, vA, 0, vB)                  // drain & compute last tile
    #undef ATT_STEP

    {
        float rl = __builtin_amdgcn_rcpf(lacc[0]);   // l for col q=l16 (rows identical)
        #pragma unroll
        for (int dt = 0; dt < 4; dt++) {
            union { u16 s[4]; uint2 v; } ok;
            #pragma unroll
            for (int r = 0; r < 4; r++) ok.s[r] = f2bf(Oacc[dt][r] * rl);
            *(uint2*)&QO[qoff + dt * 16 + quad * 4] = ok.v;
        }
    }
}

// -------- out-proj GEMM: 128m x 64n, 768 blocks, dbuf, 1 barrier/iter --------
__global__ __launch_bounds__(256) void gemm_out(
    const u16* __restrict__ Qg, const u16* __restrict__ Bt,
    const float* __restrict__ bias, float* __restrict__ out)
{
    const int K = 768;
    __shared__ __align__(16) u16 As[2][128 * 64];   // 16 KB each
    __shared__ __align__(16) u16 Bs[2][64 * 64];    // 8 KB each  (total 48 KB)

    int tid = threadIdx.x;
    int lane = tid & 63, wave = tid >> 6;
    int quad = lane >> 4, l16 = lane & 15;
    int wm = wave >> 1, wn = wave & 1;               // wave tile: 64m x 32n
    int id = blockIdx.x;
    int xcd = id & 7, j = id >> 3;                   // j in [0,96)
    int m0 = (((j & 7) << 3) + xcd) * 128;           // 64 m-tiles, XCD-pinned
    int n0 = (j >> 3) * 64;                          // 12 n-tiles

    f32x4 acc[4][2];
    #pragma unroll
    for (int i = 0; i < 4; i++)
        #pragma unroll
        for (int jj = 0; jj < 2; jj++) acc[i][jj] = (f32x4){0.f, 0.f, 0.f, 0.f};

    int r0 = tid >> 3, cg = tid & 7;
    int g = cg ^ (r0 & 7);
    const u16* GA[4]; const u16* GB[2];
    #pragma unroll
    for (int it = 0; it < 4; it++) {
        int m = m0 + it * 32 + r0, b = m >> 10, npos = m & 1023;
        GA[it] = Qg + (((size_t)(b * 12) * 1024 + npos) << 6) + g * 8;  // + h*65536
    }
    #pragma unroll
    for (int it = 0; it < 2; it++)
        GB[it] = Bt + (size_t)(n0 + it * 32 + r0) * K + g * 8;          // + kt

    #define STAGE_OUT(i2, b)                                              \
        _Pragma("unroll")                                                 \
        for (int it = 0; it < 4; it++)                                    \
            cp16(GA[it] + (size_t)(i2) * 65536, &As[b][(it * 256 + tid) * 8]); \
        _Pragma("unroll")                                                 \
        for (int it = 0; it < 2; it++)                                    \
            cp16(GB[it] + (i2) * 64,            &Bs[b][(it * 256 + tid) * 8]);

    STAGE_OUT(0, 0)
    for (int i = 0; i < 12; i++) {
        int b = i & 1;
        asm volatile("s_waitcnt vmcnt(0)" ::: "memory");   // tile i's 6 loads done
        __builtin_amdgcn_s_barrier();
        if (i + 1 < 12) { STAGE_OUT(i + 1, b ^ 1) }
        bf16x8 af[2][4], bfr[2][2];
        #pragma unroll
        for (int ko = 0; ko < 2; ko++) {
            #pragma unroll
            for (int x = 0; x < 4; x++) {
                int Ra = wm * 64 + x * 16 + l16;
                af[ko][x]  = *(const bf16x8*)&As[b][Ra * 64 + (((ko * 4 + quad) ^ (Ra & 7)) * 8)];
            }
            #pragma unroll
            for (int y = 0; y < 2; y++) {
                int Rb = wn * 32 + y * 16 + l16;
                bfr[ko][y] = *(const bf16x8*)&Bs[b][Rb * 64 + (((ko * 4 + quad) ^ (Rb & 7)) * 8)];
            }
        }
        #pragma unroll
        for (int ko = 0; ko < 2; ko++)
            #pragma unroll
            for (int x = 0; x < 4; x++)
                #pragma unroll
                for (int y = 0; y < 2; y++)
                    acc[x][y] = __builtin_amdgcn_mfma_f32_16x16x32_bf16(af[ko][x], bfr[ko][y], acc[x][y], 0, 0, 0);
    }
    #undef STAGE_OUT

    #pragma unroll
    for (int i = 0; i < 4; i++) {
        int mbase = m0 + wm * 64 + i * 16 + quad * 4;
        #pragma unroll
        for (int jj = 0; jj < 2; jj++) {
            int n = n0 + wn * 32 + jj * 16 + l16;
            float bv = bias[n];
            #pragma unroll
            for (int r = 0; r < 4; r++)
                out[(size_t)(mbase + r) * 768 + n] = acc[i][jj][r] + bv;
        }
    }
}

extern "C" void kernel_launch(void* const* d_in, const int* in_sizes, int n_in,
                              void* d_out, int out_size, void* d_ws, size_t ws_size,
                              hipStream_t stream) {
    const float* x     = (const float*)d_in[0];   // [8,1024,768] f32
    const float* w_qkv = (const float*)d_in[1];   // [768,2304] f32
    const float* w_out = (const float*)d_in[2];   // [768,768] f32
    const float* b_out = (const float*)d_in[3];   // [768] f32
    float* out = (float*)d_out;                   // [8,1024,768] f32

    char* ws = (char*)d_ws;
    u16* wtq  = (u16*)(ws);                   // [2304][768] bf16    3,538,944 B
    u16* wto  = (u16*)(ws + 3538944);         // [768][768]  bf16    1,179,648 B
    u16* Qbuf = (u16*)(ws + 4718592);         // [8,12,1024,64] bf16 12,582,912 B
    u16* xbf  = (u16*)(ws + 17301504);        // [8192][768] bf16    12,582,912 B  (29.9 MB)
    // K natural [b,h,n,64] and V TRANSPOSED [b,h,64,n] live in d_out (2x12.58 MB);
    // both fully consumed by attn128 before gemm_out overwrites d_out.
    u16* Kbuf = (u16*)d_out;
    u16* Vbuf = (u16*)d_out + 6291456;

    prep<<<dim3(5376), 256, 0, stream>>>(x, w_qkv, w_out, xbf, wtq, wto);
    gemm_qkv<<<dim3(1152), 256, 0, stream>>>(xbf, wtq, Qbuf, Kbuf, Vbuf);
    attn128<<<dim3(768), 512, 0, stream>>>(Qbuf, Kbuf, Vbuf);
    gemm_out<<<dim3(768), 256, 0, stream>>>(Qbuf, wto, b_out, out);
}

// Round 10
// 172.226 us; speedup vs baseline: 1.0550x; 1.0454x over previous
//
#include <hip/hip_runtime.h>

typedef unsigned short u16;
typedef __bf16 bf16x8 __attribute__((ext_vector_type(8)));
typedef float f32x4 __attribute__((ext_vector_type(4)));

__device__ inline u16 f2bf(float f) {
    union { float f; unsigned int u; } a; a.f = f;
    unsigned int u = a.u + 0x7fffu + ((a.u >> 16) & 1u);
    return (u16)(u >> 16);
}

// async global->LDS, 16B per lane. LDS side is wave-uniform base + lane*16.
__device__ __forceinline__ void cp16(const void* g, void* l) {
    __builtin_amdgcn_global_load_lds(
        (const __attribute__((address_space(1))) unsigned int*)g,
        (__attribute__((address_space(3))) unsigned int*)l, 16, 0, 0);
}

// -------- prep: fuse x-cast + both weight transposes (1 launch) --------
__global__ __launch_bounds__(256) void prep(
    const float* __restrict__ x, const float* __restrict__ wq,
    const float* __restrict__ wo, u16* __restrict__ xbf,
    u16* __restrict__ wtq, u16* __restrict__ wto)
{
    int bid = blockIdx.x;
    if (bid < 3072) {                      // cast x: f32 -> bf16, 8/thread
        size_t base = ((size_t)bid * 256 + threadIdx.x) * 8;
        float4 f0 = *(const float4*)&x[base];
        float4 f1 = *(const float4*)&x[base + 4];
        union { u16 s[8]; uint4 v; } t;
        t.s[0]=f2bf(f0.x); t.s[1]=f2bf(f0.y); t.s[2]=f2bf(f0.z); t.s[3]=f2bf(f0.w);
        t.s[4]=f2bf(f1.x); t.s[5]=f2bf(f1.y); t.s[6]=f2bf(f1.z); t.s[7]=f2bf(f1.w);
        *(uint4*)&xbf[base] = t.v;
        return;
    }
    __shared__ u16 tile[32][33];
    const float* in; u16* outp; int N, bx, by;
    if (bid < 3072 + 1728) { int t = bid - 3072; in = wq; outp = wtq; N = 2304; bx = t % 72; by = t / 72; }
    else                   { int t = bid - 4800; in = wo; outp = wto; N = 768;  bx = t % 24; by = t / 24; }
    int n0 = bx * 32, k0 = by * 32;
    int tx = threadIdx.x & 31, ty = threadIdx.x >> 5;
    #pragma unroll
    for (int r = ty; r < 32; r += 8)
        tile[r][tx] = f2bf(in[(size_t)(k0 + r) * N + n0 + tx]);
    __syncthreads();
    // vectorized stores: 2 adjacent k-cols per thread -> 4B/lane (was 2B/lane)
    int tx2 = threadIdx.x & 15, ty2 = threadIdx.x >> 4;
    #pragma unroll
    for (int r = ty2; r < 32; r += 16) {
        union { u16 s[2]; unsigned int v; } pk;
        pk.s[0] = tile[2 * tx2][r];
        pk.s[1] = tile[2 * tx2 + 1][r];
        *(unsigned int*)&outp[(size_t)(n0 + r) * 768 + k0 + 2 * tx2] = pk.v;
    }
}

// -------- QKV GEMM: BK=64, dbuf, counted-vmcnt pipeline (T4), XCD-pinned (R6-exact) --------
// T4 property: STAGE(i+1) issued BEFORE the counted vmcnt(8) -> tile i+1's loads stay in
// flight across the barrier + full compute phase. (R9 lesson: do not reorder this.)
// A bf16 [8192][768], Bt bf16 [2304][768]
// Q (*0.125*log2e) -> [b,h,n,64]; K -> [b,h,n,64]; V -> TRANSPOSED [b,h,d,n]
__global__ __launch_bounds__(256) void gemm_qkv(
    const u16* __restrict__ A, const u16* __restrict__ Bt,
    u16* __restrict__ q_out, u16* __restrict__ k_out, u16* __restrict__ v_out)
{
    const int K = 768;
    __shared__ __align__(16) u16 As[2][128 * 64];   // slot s of row R holds k-group s^(R&7)
    __shared__ __align__(16) u16 Bs[2][128 * 64];

    int tid = threadIdx.x;
    int lane = tid & 63, wave = tid >> 6;
    int quad = lane >> 4, l16 = lane & 15;
    int wm = wave >> 1, wn = wave & 1;
    int id = blockIdx.x;
    int xcd = id & 7, j = id >> 3;
    int m0 = (((j & 7) << 3) + xcd) * 128;   // 64 m-tiles, XCD-pinned A slabs
    int n0 = (j >> 3) * 128;                 // 18 n-tiles

    f32x4 acc[4][4];
    #pragma unroll
    for (int i = 0; i < 4; i++)
        #pragma unroll
        for (int jj = 0; jj < 4; jj++) acc[i][jj] = (f32x4){0.f, 0.f, 0.f, 0.f};

    int r0 = tid >> 3, cg = tid & 7;
    int g = cg ^ (r0 & 7);                   // row&7 == r0&7 for all 4 its
    const u16* GA[4]; const u16* GB[4];
    #pragma unroll
    for (int it = 0; it < 4; it++) {
        GA[it] = A  + (size_t)(m0 + it * 32 + r0) * K + g * 8;
        GB[it] = Bt + (size_t)(n0 + it * 32 + r0) * K + g * 8;
    }

    #define STAGE_QKV(kt, b)                                          \
        _Pragma("unroll")                                             \
        for (int it = 0; it < 4; it++) {                              \
            cp16(GA[it] + (kt), &As[b][(it * 256 + tid) * 8]);        \
            cp16(GB[it] + (kt), &Bs[b][(it * 256 + tid) * 8]);        \
        }

    STAGE_QKV(0, 0)
    for (int i = 0; i < 12; i++) {
        int b = i & 1;
        if (i + 1 < 12) {
            STAGE_QKV((i + 1) * 64, b ^ 1)
            asm volatile("s_waitcnt vmcnt(8)" ::: "memory");
        } else {
            asm volatile("s_waitcnt vmcnt(0)" ::: "memory");
        }
        __builtin_amdgcn_s_barrier();        // all waves: tile i resident in buf b
        bf16x8 af[2][4], bfr[2][4];
        #pragma unroll
        for (int ko = 0; ko < 2; ko++)
            #pragma unroll
            for (int x = 0; x < 4; x++) {
                int Ra = wm * 64 + x * 16 + l16;
                af[ko][x]  = *(const bf16x8*)&As[b][Ra * 64 + (((ko * 4 + quad) ^ (Ra & 7)) * 8)];
                int Rb = wn * 64 + x * 16 + l16;
                bfr[ko][x] = *(const bf16x8*)&Bs[b][Rb * 64 + (((ko * 4 + quad) ^ (Rb & 7)) * 8)];
            }
        #pragma unroll
        for (int ko = 0; ko < 2; ko++)
            #pragma unroll
            for (int x = 0; x < 4; x++)
                #pragma unroll
                for (int y = 0; y < 4; y++)
                    acc[x][y] = __builtin_amdgcn_mfma_f32_16x16x32_bf16(af[ko][x], bfr[ko][y], acc[x][y], 0, 0, 0);
        __builtin_amdgcn_s_barrier();        // WAR: buf b fully read before iter i+1 overwrites it
    }
    #undef STAGE_QKV

    // ---- epilogue: wave tile = 64m x 64n, one (part,h); per-wave LDS region in buf0 ----
    int M0 = m0 + wm * 64, N0 = n0 + wn * 64;
    int part = N0 >= 1536 ? 2 : (N0 >= 768 ? 1 : 0);
    int h = (N0 - part * 768) >> 6;
    int b2 = M0 >> 10, npos0 = M0 & 1023;
    u16* ep = (wave < 2 ? As[0] : Bs[0]) + (wave & 1) * 4096;   // 8 KB per wave (buf0: free)

    if (part != 2) {
        float scale = (part == 0) ? 0.18033688011112042f : 1.0f;   // /8 * log2e for Q
        u16* gbase = (part == 0 ? q_out : k_out) + (((size_t)(b2 * 12 + h) * 1024 + npos0) << 6);
        #pragma unroll
        for (int i = 0; i < 4; i++)
            #pragma unroll
            for (int jj = 0; jj < 4; jj++) {
                int dd = jj * 16 + l16;
                #pragma unroll
                for (int r = 0; r < 4; r++) {
                    int np = i * 16 + quad * 4 + r;
                    ep[np * 64 + (((dd >> 3) ^ (np & 7)) * 8) + (dd & 7)] =
                        f2bf(acc[i][jj][r] * scale);
                }
            }
        #pragma unroll
        for (int t = 0; t < 8; t++) {        // per-wave region: ds order suffices, no barrier
            int idx = t * 512 + lane * 8;
            int np = idx >> 6;
            int slot = ((lane & 7) ^ (np & 7));
            uint4 v = *(const uint4*)&ep[np * 64 + slot * 8];
            *(uint4*)&gbase[idx] = v;
        }
    } else {
        #pragma unroll
        for (int i = 0; i < 4; i++)
            #pragma unroll
            for (int jj = 0; jj < 4; jj++) {
                int dd = jj * 16 + l16;
                int npg = i * 2 + (quad >> 1);
                int sub = (quad & 1) * 4;
                union { u16 s[4]; uint2 v; } pk;
                #pragma unroll
                for (int r = 0; r < 4; r++) pk.s[r] = f2bf(acc[i][jj][r]);
                *(uint2*)&ep[dd * 64 + ((npg ^ (dd & 7)) * 8) + sub] = pk.v;
            }
        #pragma unroll
        for (int t = 0; t < 8; t++) {
            int dd = t * 8 + (lane >> 3);
            int npg = lane & 7;
            uint4 v = *(const uint4*)&ep[dd * 64 + ((npg ^ (dd & 7)) * 8)];
            *(uint4*)&v_out[((size_t)((b2 * 12 + h) * 64 + dd)) * 1024 + npos0 + npg * 8] = v;
        }
    }
}

// -------- attention: 8 waves (512 thr), 16 q/wave, 1 barrier/iter (R4-exact FROZEN text) --------
__global__ __launch_bounds__(512, 6) void attn128(
    u16* __restrict__ QO, const u16* __restrict__ Kg, const u16* __restrict__ Vtg)
{
    __shared__ __align__(16) u16 Ks[2][64 * 64];   // [kv][d], 16B groups at pos g^(row&7)
    __shared__ __align__(16) u16 Vs[2][64 * 64];   // [d][kv], 8B chunks at pos c^(d&15)

    int tid = threadIdx.x;
    int lane = tid & 63, wave = tid >> 6;          // 8 waves
    int quad = lane >> 4, l16 = lane & 15;
    int id = blockIdx.x;
    int xcd = id & 7, j = id >> 3;                 // 12 heads per XCD
    int bh = xcd * 12 + (j >> 3);
    int q0 = (j & 7) * 128;
    const size_t head_base = (size_t)bh * 65536;

    size_t qoff = head_base + (size_t)(q0 + wave * 16 + l16) * 64;
    bf16x8 qf0 = *(const bf16x8*)&QO[qoff + quad * 8];
    bf16x8 qf1 = *(const bf16x8*)&QO[qoff + 32 + quad * 8];

    f32x4 Oacc[4];
    #pragma unroll
    for (int dt = 0; dt < 4; dt++) Oacc[dt] = (f32x4){0.f, 0.f, 0.f, 0.f};
    f32x4 lacc = (f32x4){0.f, 0.f, 0.f, 0.f};

    // ones A-fragment for l = sum_k P[k][q] via MFMA
    union { unsigned int w[4]; bf16x8 v; } ones;
    ones.w[0] = ones.w[1] = ones.w[2] = ones.w[3] = 0x3f803f80u;

    int srow = tid >> 3, sg = tid & 7;             // 512 thr cover 64 rows x 128B
    int gsK = sg ^ (srow & 7);
    const u16* GK = Kg + head_base + (size_t)srow * 64 + gsK * 8;
    const u16* GV = Vtg + head_base + (size_t)srow * 1024 + sg * 8;
    const int vwA = srow * 64 + (((2 * sg)     ^ (srow & 15)) * 4);
    const int vwB = srow * 64 + (((2 * sg + 1) ^ (srow & 15)) * 4);

    uint4 vA, vB;
    // prologue: V(0) -> LDS direct; V(1) -> regs; K(0) cp16
    {
        uint4 t0 = *(const uint4*)GV;
        uint2 t;
        t.x = t0.x; t.y = t0.y; *(uint2*)&Vs[0][vwA] = t;
        t.x = t0.z; t.y = t0.w; *(uint2*)&Vs[0][vwB] = t;
    }
    vA = *(const uint4*)(GV + 64);
    cp16(GK, &Ks[0][tid * 8]);

    // one barrier per iter; prefetch issued after it, drained at next iter's vmcnt(0)
    #define ATT_STEP(I, DO_K, DO_LD, VLD, DO_WR, VWR)                            \
    {                                                                            \
        const int b = (I) & 1;                                                   \
        asm volatile("s_waitcnt vmcnt(0)" ::: "memory");                         \
        asm volatile("s_waitcnt lgkmcnt(0)" ::: "memory");                       \
        __builtin_amdgcn_s_barrier();                                            \
        if (DO_K) cp16(GK + (size_t)((I) + 1) * 4096, &Ks[b ^ 1][tid * 8]);      \
        if (DO_LD) VLD = *(const uint4*)(GV + ((I) + 2) * 64);                   \
        if (DO_WR) {                                                             \
            uint2 t;                                                             \
            t.x = VWR.x; t.y = VWR.y; *(uint2*)&Vs[b ^ 1][vwA] = t;              \
            t.x = VWR.z; t.y = VWR.w; *(uint2*)&Vs[b ^ 1][vwB] = t;              \
        }                                                                        \
        f32x4 s4[4];                                                             \
        _Pragma("unroll")                                                        \
        for (int nt = 0; nt < 4; nt++) {                                         \
            int R = nt * 16 + l16;                                               \
            bf16x8 kf0 = *(const bf16x8*)&Ks[b][R * 64 + ((quad       ^ (R & 7)) * 8)]; \
            bf16x8 kf1 = *(const bf16x8*)&Ks[b][R * 64 + (((quad + 4) ^ (R & 7)) * 8)]; \
            f32x4 s = (f32x4){0.f, 0.f, 0.f, 0.f};                               \
            s = __builtin_amdgcn_mfma_f32_16x16x32_bf16(kf0, qf0, s, 0, 0, 0);   \
            s = __builtin_amdgcn_mfma_f32_16x16x32_bf16(kf1, qf1, s, 0, 0, 0);   \
            s4[nt] = s;                                                          \
        }                                                                        \
        float p[4][4];                                                           \
        _Pragma("unroll")                                                        \
        for (int nt = 0; nt < 4; nt++)                                           \
            _Pragma("unroll")                                                    \
            for (int r = 0; r < 4; r++)                                          \
                p[nt][r] = __builtin_amdgcn_exp2f(s4[nt][r]);                    \
        __builtin_amdgcn_s_setprio(1);                                           \
        _Pragma("unroll")                                                        \
        for (int h = 0; h < 2; h++) {                                            \
            union { unsigned int w[4]; bf16x8 v; } pk;                           \
            asm("v_cvt_pk_bf16_f32 %0, %1, %2" : "=v"(pk.w[0]) : "v"(p[2*h][0]),   "v"(p[2*h][1]));   \
            asm("v_cvt_pk_bf16_f32 %0, %1, %2" : "=v"(pk.w[1]) : "v"(p[2*h][2]),   "v"(p[2*h][3]));   \
            asm("v_cvt_pk_bf16_f32 %0, %1, %2" : "=v"(pk.w[2]) : "v"(p[2*h+1][0]), "v"(p[2*h+1][1])); \
            asm("v_cvt_pk_bf16_f32 %0, %1, %2" : "=v"(pk.w[3]) : "v"(p[2*h+1][2]), "v"(p[2*h+1][3])); \
            lacc = __builtin_amdgcn_mfma_f32_16x16x32_bf16(ones.v, pk.v, lacc, 0, 0, 0); \
            int pbase = ((8 * h + quad) ^ l16) * 4;                              \
            _Pragma("unroll")                                                    \
            for (int dt = 0; dt < 4; dt++) {                                     \
                int drow = dt * 16 + l16;                                        \
                union { u16 s[8]; bf16x8 v; } vk;                                \
                *(uint2*)&vk.s[0] = *(const uint2*)&Vs[b][drow * 64 + pbase];    \
                *(uint2*)&vk.s[4] = *(const uint2*)&Vs[b][drow * 64 + (pbase ^ 16)]; \
                Oacc[dt] = __builtin_amdgcn_mfma_f32_16x16x32_bf16(vk.v, pk.v, Oacc[dt], 0, 0, 0); \
            }                                                                    \
        }                                                                        \
        __builtin_amdgcn_s_setprio(0);                                           \
    }

    // main: unrolled x2 so V reg sets alternate with no copies
    for (int ii = 0; ii < 7; ii++) {
        ATT_STEP(2 * ii,     1, 1, vB, 1, vA)      // write V(i+1)=vA, load V(i+2)->vB
        ATT_STEP(2 * ii + 1, 1, 1, vA, 1, vB)
    }
    ATT_STEP(14, 1, 0, vB, 1, vA)                  // K(15) only; write V(15)=vA
    ATT_STEP(15, 0, 0, vA, 0, vB)                  // drain & compute last tile
    #undef ATT_STEP

    {
        float rl = __builtin_amdgcn_rcpf(lacc[0]);   // l for col q=l16 (rows identical)
        #pragma unroll
        for (int dt = 0; dt < 4; dt++) {
            union { u16 s[4]; uint2 v; } ok;
            #pragma unroll
            for (int r = 0; r < 4; r++) ok.s[r] = f2bf(Oacc[dt][r] * rl);
            *(uint2*)&QO[qoff + dt * 16 + quad * 4] = ok.v;
        }
    }
}

// -------- out-proj GEMM: 128m x 64n, 768 blocks (3.0/CU), dbuf counted-vmcnt (R6-exact) --------
__global__ __launch_bounds__(256) void gemm_out(
    const u16* __restrict__ Qg, const u16* __restrict__ Bt,
    const float* __restrict__ bias, float* __restrict__ out)
{
    const int K = 768;
    __shared__ __align__(16) u16 As[2][128 * 64];   // 16 KB each
    __shared__ __align__(16) u16 Bs[2][64 * 64];    // 8 KB each  (total 48 KB)

    int tid = threadIdx.x;
    int lane = tid & 63, wave = tid >> 6;
    int quad = lane >> 4, l16 = lane & 15;
    int wm = wave >> 1, wn = wave & 1;               // wave tile: 64m x 32n
    int id = blockIdx.x;
    int xcd = id & 7, j = id >> 3;                   // j in [0,96)
    int m0 = (((j & 7) << 3) + xcd) * 128;           // 64 m-tiles, XCD-pinned
    int n0 = (j >> 3) * 64;                          // 12 n-tiles

    f32x4 acc[4][2];
    #pragma unroll
    for (int i = 0; i < 4; i++)
        #pragma unroll
        for (int jj = 0; jj < 2; jj++) acc[i][jj] = (f32x4){0.f, 0.f, 0.f, 0.f};

    int r0 = tid >> 3, cg = tid & 7;
    int g = cg ^ (r0 & 7);
    const u16* GA[4]; const u16* GB[2];
    #pragma unroll
    for (int it = 0; it < 4; it++) {
        int m = m0 + it * 32 + r0, b = m >> 10, npos = m & 1023;
        GA[it] = Qg + (((size_t)(b * 12) * 1024 + npos) << 6) + g * 8;  // + h*65536
    }
    #pragma unroll
    for (int it = 0; it < 2; it++)
        GB[it] = Bt + (size_t)(n0 + it * 32 + r0) * K + g * 8;          // + kt

    #define STAGE_OUT(i2, b)                                              \
        _Pragma("unroll")                                                 \
        for (int it = 0; it < 4; it++)                                    \
            cp16(GA[it] + (size_t)(i2) * 65536, &As[b][(it * 256 + tid) * 8]); \
        _Pragma("unroll")                                                 \
        for (int it = 0; it < 2; it++)                                    \
            cp16(GB[it] + (i2) * 64,            &Bs[b][(it * 256 + tid) * 8]);

    STAGE_OUT(0, 0)
    for (int i = 0; i < 12; i++) {
        int b = i & 1;
        if (i + 1 < 12) {
            STAGE_OUT(i + 1, b ^ 1)
            asm volatile("s_waitcnt vmcnt(6)" ::: "memory");
        } else {
            asm volatile("s_waitcnt vmcnt(0)" ::: "memory");
        }
        __builtin_amdgcn_s_barrier();
        bf16x8 af[2][4], bfr[2][2];
        #pragma unroll
        for (int ko = 0; ko < 2; ko++) {
            #pragma unroll
            for (int x = 0; x < 4; x++) {
                int Ra = wm * 64 + x * 16 + l16;
                af[ko][x]  = *(const bf16x8*)&As[b][Ra * 64 + (((ko * 4 + quad) ^ (Ra & 7)) * 8)];
            }
            #pragma unroll
            for (int y = 0; y < 2; y++) {
                int Rb = wn * 32 + y * 16 + l16;
                bfr[ko][y] = *(const bf16x8*)&Bs[b][Rb * 64 + (((ko * 4 + quad) ^ (Rb & 7)) * 8)];
            }
        }
        #pragma unroll
        for (int ko = 0; ko < 2; ko++)
            #pragma unroll
            for (int x = 0; x < 4; x++)
                #pragma unroll
                for (int y = 0; y < 2; y++)
                    acc[x][y] = __builtin_amdgcn_mfma_f32_16x16x32_bf16(af[ko][x], bfr[ko][y], acc[x][y], 0, 0, 0);
        __builtin_amdgcn_s_barrier();
    }
    #undef STAGE_OUT

    #pragma unroll
    for (int i = 0; i < 4; i++) {
        int mbase = m0 + wm * 64 + i * 16 + quad * 4;
        #pragma unroll
        for (int jj = 0; jj < 2; jj++) {
            int n = n0 + wn * 32 + jj * 16 + l16;
            float bv = bias[n];
            #pragma unroll
            for (int r = 0; r < 4; r++)
                out[(size_t)(mbase + r) * 768 + n] = acc[i][jj][r] + bv;
        }
    }
}

extern "C" void kernel_launch(void* const* d_in, const int* in_sizes, int n_in,
                              void* d_out, int out_size, void* d_ws, size_t ws_size,
                              hipStream_t stream) {
    const float* x     = (const float*)d_in[0];   // [8,1024,768] f32
    const float* w_qkv = (const float*)d_in[1];   // [768,2304] f32
    const float* w_out = (const float*)d_in[2];   // [768,768] f32
    const float* b_out = (const float*)d_in[3];   // [768] f32
    float* out = (float*)d_out;                   // [8,1024,768] f32

    char* ws = (char*)d_ws;
    u16* wtq  = (u16*)(ws);                   // [2304][768] bf16    3,538,944 B
    u16* wto  = (u16*)(ws + 3538944);         // [768][768]  bf16    1,179,648 B
    u16* Qbuf = (u16*)(ws + 4718592);         // [8,12,1024,64] bf16 12,582,912 B
    u16* xbf  = (u16*)(ws + 17301504);        // [8192][768] bf16    12,582,912 B  (29.9 MB)
    // K natural [b,h,n,64] and V TRANSPOSED [b,h,64,n] live in d_out (2x12.58 MB);
    // both fully consumed by attn128 before gemm_out overwrites d_out.
    u16* Kbuf = (u16*)d_out;
    u16* Vbuf = (u16*)d_out + 6291456;

    prep<<<dim3(5376), 256, 0, stream>>>(x, w_qkv, w_out, xbf, wtq, wto);
    gemm_qkv<<<dim3(1152), 256, 0, stream>>>(xbf, wtq, Qbuf, Kbuf, Vbuf);
    attn128<<<dim3(768), 512, 0, stream>>>(Qbuf, Kbuf, Vbuf);
    gemm_out<<<dim3(768), 256, 0, stream>>>(Qbuf, wto, b_out, out);
}